// Round 9
// baseline (174.325 us; speedup 1.0000x reference)
//
#include <hip/hip_runtime.h>
#include <hip/hip_bf16.h>

#define TSEQ 2048
#define CEMB 1024

typedef __attribute__((ext_vector_type(8))) short bf16x8;
typedef __attribute__((ext_vector_type(4))) float f32x4;
typedef __attribute__((ext_vector_type(16))) float f32x16;
typedef __attribute__((ext_vector_type(4))) int i32x4;

__device__ __forceinline__ unsigned short f2bf(float f){
  return __builtin_bit_cast(unsigned short, __float2bfloat16(f));
}

__device__ __forceinline__ f32x4 MFMA16(bf16x8 a, bf16x8 b, f32x4 c){
  return __builtin_amdgcn_mfma_f32_16x16x32_bf16(a, b, c, 0, 0, 0);
}

#define GLDS(src, dst) __builtin_amdgcn_global_load_lds( \
      (const __attribute__((address_space(1))) void*)(src), \
      (__attribute__((address_space(3))) void*)(dst), 16, 0, 0)

template<int N> __device__ __forceinline__ void vmwait(){
  if constexpr (N == 0) asm volatile("s_waitcnt vmcnt(0)" ::: "memory");
  else if constexpr (N == 6) asm volatile("s_waitcnt vmcnt(6)" ::: "memory");
  else if constexpr (N == 7) asm volatile("s_waitcnt vmcnt(7)" ::: "memory");
  else asm volatile("s_waitcnt vmcnt(8)" ::: "memory");
}

// ---------- fused prep: x->bf16 cast + both weight transposes ----------
// blocks [0,8192): cvt; [8192,11264): w_qkv^T; [11264,12288): w_out^T
__global__ __launch_bounds__(256) void k_prep(
    const float* __restrict__ x, unsigned short* __restrict__ xb,
    const float* __restrict__ w_qkv, unsigned short* __restrict__ wqkvT,
    const float* __restrict__ w_out, unsigned short* __restrict__ woutT)
{
  __shared__ unsigned short tile[32][33];
  const int bid = blockIdx.x, tid = threadIdx.x;
  if (bid < 8192){
    const int i = bid * 256 + tid;
    const float4 v = reinterpret_cast<const float4*>(x)[i];
    ushort4 o;
    o.x = f2bf(v.x); o.y = f2bf(v.y); o.z = f2bf(v.z); o.w = f2bf(v.w);
    reinterpret_cast<ushort4*>(xb)[i] = o;
    return;
  }
  const float* w; unsigned short* wT; int N, n0, k0;
  if (bid < 11264){
    const int b2 = bid - 8192;           // 3072 blocks, N=3072
    w = w_qkv; wT = wqkvT; N = 3072;
    n0 = (b2 % 96) * 32; k0 = (b2 / 96) * 32;
  } else {
    const int b3 = bid - 11264;          // 1024 blocks, N=1024
    w = w_out; wT = woutT; N = 1024;
    n0 = (b3 & 31) * 32; k0 = (b3 >> 5) * 32;
  }
  const int tx = tid & 31, ty = tid >> 5;
  #pragma unroll
  for (int r = 0; r < 4; ++r){
    int k = ty * 4 + r;
    tile[k][tx] = f2bf(w[(size_t)(k0 + k) * N + n0 + tx]);
  }
  __syncthreads();
  #pragma unroll
  for (int r = 0; r < 4; ++r){
    int n = ty * 4 + r;
    wT[(size_t)(n0 + n) * 1024 + k0 + tx] = tile[tx][n];
  }
}

// ---------- V head-transpose: qkv[t][2048+h*64+d] -> vT[(bh*64+d)][t] ----------
__global__ __launch_bounds__(256) void k_vT(const unsigned short* __restrict__ qkv,
                                            unsigned short* __restrict__ vT){
  __shared__ __align__(16) unsigned short tile[64*64];
  const int tid = threadIdx.x;
  const int bh = blockIdx.x;          // b*16+h
  const int t0 = blockIdx.y * 64;
  const int b = bh >> 4, h = bh & 15;
  const int lt = tid >> 3, seg = tid & 7;
  #pragma unroll
  for (int r = 0; r < 2; ++r){
    const int t = lt + 32*r;
    const i32x4 v = *(const i32x4*)&qkv[((size_t)(b*TSEQ + t0 + t))*3072 + 2048 + h*64 + seg*8];
    const int slot = seg ^ (t & 7) ^ (t >> 3);
    *(i32x4*)((char*)tile + t*128 + slot*16) = v;
  }
  __syncthreads();
  const int w = tid >> 6, lane = tid & 63;
  const int tseg = lane & 7;
  #pragma unroll
  for (int r = 0; r < 2; ++r){
    const int d = w*8 + (lane>>3) + 32*r;
    unsigned int wd[4];
    #pragma unroll
    for (int jp = 0; jp < 4; ++jp){
      unsigned int lo, hi;
      #pragma unroll
      for (int e = 0; e < 2; ++e){
        const int j = jp*2 + e;
        const int t = tseg*8 + j;
        const int byteoff = t*128 + ((2*d) ^ (((j ^ tseg) & 7) << 4));
        const unsigned int val = *(const unsigned short*)((const char*)tile + byteoff);
        if (e == 0) lo = val; else hi = val;
      }
      wd[jp] = lo | (hi << 16);
    }
    i32x4 o4; o4[0]=wd[0]; o4[1]=wd[1]; o4[2]=wd[2]; o4[3]=wd[3];
    *(i32x4*)&vT[((size_t)bh*64 + d)*2048 + t0 + tseg*8] = o4;
  }
}

// ---------- GEMM 256xBN deep-pipelined (T1+T2+T3+T4+T5) — unchanged ----------
template<bool OUT_BF16, int BN>
__global__ __launch_bounds__(512, 2) void k_gemm256(
    const unsigned short* __restrict__ A,
    const unsigned short* __restrict__ Bt,
    const float* __restrict__ bias,
    void* __restrict__ Cout, int M, int N, int K)
{
  constexpr int NW  = BN / 64;
  constexpr int NH0 = (NW + 1) / 2;
  constexpr int NL  = 4 + NW;
  constexpr int BNB = BN * 128;
  __shared__ __align__(16) char smem[65536 + 2 * BNB];

  const int tid = threadIdx.x;
  const int lane = tid & 63, w = tid >> 6;
  const int wm = w >> 2, wn = w & 3;
  const int l15 = lane & 15, l4 = lane >> 4;
  const int x7 = l15 & 7;

  unsigned lin = blockIdx.x;
  {
    const unsigned nwg = gridDim.x;
    const unsigned qq = nwg >> 3, rr = nwg & 7;
    const unsigned xcd = lin & 7, loc = lin >> 3;
    lin = (xcd < rr ? xcd * (qq + 1) : rr * (qq + 1) + (xcd - rr) * qq) + loc;
  }
  const unsigned ntn = (unsigned)N / BN;
  const int m0 = (int)(lin / ntn) << 8;
  const int n0 = (int)(lin % ntn) * BN;

  const int srow = lane >> 3;
  const int scx  = (lane & 7) ^ srow;
  const unsigned short* Ag = A  + (size_t)(m0 + w*8 + srow) * K + scx * 8;
  const unsigned short* Bg = Bt + (size_t)(n0 + w*8 + srow) * K + scx * 8;

  auto stageA = [&](int buf, int kt){
    const unsigned short* s = Ag + kt*64;
    char* d = smem + buf*32768 + (w << 10);
    #pragma unroll
    for (int i = 0; i < 4; ++i) GLDS(s + (size_t)(i*64)*K, d + i*8192);
  };
  auto stageB = [&](int buf, int kt){
    const unsigned short* s = Bg + kt*64;
    char* d = smem + 65536 + buf*BNB + (w << 10);
    #pragma unroll
    for (int i = 0; i < NW; ++i) GLDS(s + (size_t)(i*64)*K, d + i*8192);
  };

  const int arow = wm*128 + l15;
  const int brow = wn*(BN/4) + l15;
  auto rdA = [&](int buf, int m, int ks)->bf16x8 {
    return *(const bf16x8*)(smem + buf*32768 + (arow + m*16)*128 + (((ks*4 + l4) ^ x7) << 4));
  };
  auto rdB = [&](int buf, int n, int ks)->bf16x8 {
    return *(const bf16x8*)(smem + 65536 + buf*BNB + (brow + n*16)*128 + (((ks*4 + l4) ^ x7) << 4));
  };

  f32x4 acc[8][NW] = {};
  const int NIT = K >> 7;

  stageA(0, 0); stageB(0, 0);
  stageA(1, 1); stageB(1, 1);
  vmwait<NL>();
  __builtin_amdgcn_s_barrier();
  asm volatile("" ::: "memory");

  for (int it = 0; it < NIT; ++it){
    const bool more = (it + 1 < NIT);
    #pragma unroll
    for (int half = 0; half < 2; ++half){
      const int buf = half;
      bf16x8 bfr[NW][2], af1[4][2], af2[4][2];
      #pragma unroll
      for (int n = 0; n < NW; ++n){ bfr[n][0] = rdB(buf, n, 0); bfr[n][1] = rdB(buf, n, 1); }
      #pragma unroll
      for (int m = 0; m < 4; ++m){ af1[m][0] = rdA(buf, m, 0); af1[m][1] = rdA(buf, m, 1); }
      __builtin_amdgcn_s_setprio(1);
      #pragma unroll
      for (int m = 0; m < 4; ++m)
        #pragma unroll
        for (int n = 0; n < NH0; ++n)
          #pragma unroll
          for (int ks = 0; ks < 2; ++ks)
            acc[m][n] = MFMA16(af1[m][ks], bfr[n][ks], acc[m][n]);
      __builtin_amdgcn_s_setprio(0);
      #pragma unroll
      for (int m = 0; m < 4; ++m){ af2[m][0] = rdA(buf, m+4, 0); af2[m][1] = rdA(buf, m+4, 1); }
      __builtin_amdgcn_s_setprio(1);
      #pragma unroll
      for (int m = 0; m < 4; ++m)
        #pragma unroll
        for (int n = NH0; n < NW; ++n)
          #pragma unroll
          for (int ks = 0; ks < 2; ++ks)
            acc[m][n] = MFMA16(af1[m][ks], bfr[n][ks], acc[m][n]);
      __builtin_amdgcn_s_setprio(0);
      __builtin_amdgcn_s_setprio(1);
      #pragma unroll
      for (int m = 0; m < 4; ++m)
        #pragma unroll
        for (int n = NH0; n < NW; ++n)
          #pragma unroll
          for (int ks = 0; ks < 2; ++ks)
            acc[m+4][n] = MFMA16(af2[m][ks], bfr[n][ks], acc[m+4][n]);
      __builtin_amdgcn_s_setprio(0);
      asm volatile("s_waitcnt lgkmcnt(0)" ::: "memory");
      __builtin_amdgcn_s_barrier();
      asm volatile("" ::: "memory");
      if (more){ stageA(buf, 2*it + half + 2); stageB(buf, 2*it + half + 2); }
      __builtin_amdgcn_s_setprio(1);
      #pragma unroll
      for (int m = 0; m < 4; ++m)
        #pragma unroll
        for (int n = 0; n < NH0; ++n)
          #pragma unroll
          for (int ks = 0; ks < 2; ++ks)
            acc[m+4][n] = MFMA16(af2[m][ks], bfr[n][ks], acc[m+4][n]);
      __builtin_amdgcn_s_setprio(0);
      if (more) vmwait<NL>();
      else      vmwait<0>();
      __builtin_amdgcn_s_barrier();
      asm volatile("" ::: "memory");
    }
  }

  float bv[NW];
  #pragma unroll
  for (int n = 0; n < NW; ++n) bv[n] = bias[n0 + wn*(BN/4) + n*16 + l15];

  #pragma unroll
  for (int m = 0; m < 8; ++m){
    const int row = m0 + wm*128 + m*16 + l4*4;
    #pragma unroll
    for (int n = 0; n < NW; ++n){
      const int col = n0 + wn*(BN/4) + n*16 + l15;
      #pragma unroll
      for (int r = 0; r < 4; ++r){
        float v = acc[m][n][r] + bv[n];
        if (OUT_BF16)
          ((unsigned short*)Cout)[(size_t)(row + r) * N + col] = f2bf(v);
        else
          ((float*)Cout)[(size_t)(row + r) * N + col] = v;
      }
    }
  }
}

// ---------- causal flash attention v7: balanced 17/17 kv-work split ----------
// Block (bh, p): q-tiles tA=p, tB=15-p. Concatenated kv queue (34 tiles) split
// exactly: group A (waves 0-3) = tile A's 2p+2 tiles + tile B kv[0,15-2p);
// group B (waves 4-7) = tile B kv[15-2p, 32-2p). Every block: 17 iterations,
// all waves busy. Shift-free softmax makes tile-B partials additive; combine
// via LDS (stride-33 pad). Each group has its own K/V double buffer (64 KB).
__global__ __launch_bounds__(512, 4) void k_attn(
    const unsigned short* __restrict__ qkv,
    const unsigned short* __restrict__ vT,
    unsigned short* __restrict__ y)
{
  __shared__ __align__(16) char smem[65536];  // [group][buf][K|V] = 2*2*16KB
  __shared__ float Ls[8][32];
  __shared__ float lB[4][32];

  const int tid = threadIdx.x, lane = tid & 63, w = tid >> 6;  // w 0..7
  const int q31 = lane & 31, hi = lane >> 5;
  const int bh = blockIdx.x, p = blockIdx.y;    // p in [0,8)
  const int g = w >> 2, wl = w & 3;
  const int tA = p, tB = 15 - p;
  const int b = bh >> 4, h = bh & 15;
  const size_t rowB = (size_t)b * TSEQ;
  const int nktA = 2*p + 2;

  const float sc = 0.18033688011112042f;   // (1/sqrt(64)) * log2(e)

  // current-tile state (group A switches tiles mid-loop)
  int wq0 = (g ? tB : tA) * 128 + 32 * wl;

  bf16x8 qf[4];
  auto loadQ = [&](int qgx){
    const unsigned short* qp = qkv + (rowB + qgx) * 3072 + h * 64;
    #pragma unroll
    for (int c4 = 0; c4 < 4; ++c4){
      bf16x8 v = *(const bf16x8*)(qp + c4*16 + hi*8);
      #pragma unroll
      for (int j = 0; j < 8; ++j){
        const unsigned int bits = ((unsigned int)(unsigned short)v[j]) << 16;
        v[j] = (short)f2bf(__builtin_bit_cast(float, bits) * sc);
      }
      qf[c4] = v;
    }
  };
  loadQ(wq0 + q31);

  // group-local staging: 4 waves cover 64 rows x 8 chunks via 2 insts/matrix
  const int kr = lane >> 3, cx = (lane & 7) ^ kr;
  const unsigned short* kgbase = qkv + (rowB + wl*8 + kr) * 3072 + 1024 + h*64 + cx*8;
  const unsigned short* vgbase = vT + ((size_t)bh*64 + wl*8 + kr) * 2048 + cx*8;
  char* const gKV = smem + g*32768;

  auto stage = [&](int kv, int buf){
    char* kb = gKV + buf*16384;
    #pragma unroll
    for (int j = 0; j < 2; ++j){
      GLDS(kgbase + (size_t)kv*64*3072 + (size_t)j*32*3072, kb + j*4096 + wl*1024);
      GLDS(vgbase + (size_t)kv*64      + (size_t)j*32*2048, kb + 8192 + j*4096 + wl*1024);
    }
  };
  // work queue: group A: i<nktA ? i : i-nktA ; group B: i + 15-2p
  auto kv_of = [&](int i)->int {
    return g ? (i + 15 - 2*p) : (i < nktA ? i : i - nktA);
  };

  f32x16 O[2] = {};
  float l = 0.f;

  // wave-private finalize of current (O,l) -> y rows [wq0s, wq0s+32)
  auto storeY = [&](int wq0s){
    const float lc = l + __shfl_xor(l, 32);
    if (lane < 32) Ls[w][lane] = 1.0f / lc;
    asm volatile("s_waitcnt lgkmcnt(0)" ::: "memory");
    #pragma unroll
    for (int r = 0; r < 16; ++r){
      const int qloc = (r&3) + 8*(r>>2) + 4*hi;
      const float inv = Ls[w][qloc];
      const size_t row = rowB + wq0s + qloc;
      #pragma unroll
      for (int dblk = 0; dblk < 2; ++dblk)
        y[row * CEMB + h*64 + dblk*32 + q31] = f2bf(O[dblk][r] * inv);
    }
  };

  stage(kv_of(0), 0);
  __syncthreads();

  int cbuf = 0;
  for (int i = 0; i < 17; ++i){
    if (i + 1 < 17) stage(kv_of(i + 1), cbuf ^ 1);

    // group A: tile switch at i == nktA (finalize A, start B partials)
    if (!g && i == nktA){
      storeY(tA*128 + 32*wl);
      #pragma unroll
      for (int dblk = 0; dblk < 2; ++dblk) O[dblk] = (f32x16){};
      l = 0.f;
      wq0 = tB*128 + 32*wl;
      loadQ(wq0 + q31);
    }

    const int kv = kv_of(i);
    const int qg = wq0 + q31;
    const char* kb = gKV + cbuf*16384;
    const char* vb = kb + 8192;
    const bool domask = (kv*64 + 63 > wq0);
    #pragma unroll
    for (int sub = 0; sub < 2; ++sub){
      f32x16 S = {};
      __builtin_amdgcn_s_setprio(1);
      #pragma unroll
      for (int c4 = 0; c4 < 4; ++c4){
        const bf16x8 kf = *(const bf16x8*)(kb + (sub*32 + q31)*128
                              + ((((c4<<1)|hi) ^ (q31 & 7)) << 4));
        S = __builtin_amdgcn_mfma_f32_32x32x16_bf16(kf, qf[c4], S, 0, 0, 0);
      }
      __builtin_amdgcn_s_setprio(0);
      if (domask){
        #pragma unroll
        for (int r = 0; r < 16; ++r){
          const int kg = kv*64 + sub*32 + (r&3) + 8*(r>>2) + 4*hi;
          if (kg > qg) S[r] = -1e30f;
        }
      }
      float ps = 0.f;
      #pragma unroll
      for (int r = 0; r < 16; ++r){
        S[r] = __builtin_amdgcn_exp2f(S[r]);
        ps += S[r];
      }
      l += ps;
      bf16x8 paf[2];
      #pragma unroll
      for (int kc = 0; kc < 2; ++kc){
        const int e = kc * 8;
        unsigned int a, bb, cc, dd;
        asm("v_cvt_pk_bf16_f32 %0, %1, %2" : "=v"(a)  : "v"(S[e+0]), "v"(S[e+1]));
        asm("v_cvt_pk_bf16_f32 %0, %1, %2" : "=v"(bb) : "v"(S[e+4]), "v"(S[e+5]));
        asm("v_cvt_pk_bf16_f32 %0, %1, %2" : "=v"(cc) : "v"(S[e+2]), "v"(S[e+3]));
        asm("v_cvt_pk_bf16_f32 %0, %1, %2" : "=v"(dd) : "v"(S[e+6]), "v"(S[e+7]));
        asm volatile("v_permlane32_swap_b32 %0, %1" : "+v"(a),  "+v"(bb));
        asm volatile("v_permlane32_swap_b32 %0, %1" : "+v"(cc), "+v"(dd));
        i32x4 pwv; pwv[0] = (int)a; pwv[1] = (int)cc; pwv[2] = (int)bb; pwv[3] = (int)dd;
        paf[kc] = __builtin_bit_cast(bf16x8, pwv);
      }
      __builtin_amdgcn_s_setprio(1);
      #pragma unroll
      for (int kc = 0; kc < 2; ++kc){
        #pragma unroll
        for (int dblk = 0; dblk < 2; ++dblk){
          const int dr = dblk*32 + q31;
          const bf16x8 vf = *(const bf16x8*)(vb + dr*128
                                + ((((sub<<2)|(kc<<1)|hi) ^ (dr & 7)) << 4));
          O[dblk] = __builtin_amdgcn_mfma_f32_32x32x16_bf16(paf[kc], vf, O[dblk], 0, 0, 0);
        }
      }
      __builtin_amdgcn_s_setprio(0);
    }

    __syncthreads();   // drains gload_lds; publishes next buffer (both groups)
    cbuf ^= 1;
  }

  // ---- combine tile-B partials: group A -> LDS, group B adds & stores ----
  float* cb = (float*)smem;                       // staging done; reuse
  if (!g){
    float* dst = cb + (size_t)(wl*64 + lane) * 33;
    #pragma unroll
    for (int dblk = 0; dblk < 2; ++dblk)
      #pragma unroll
      for (int r = 0; r < 16; ++r) dst[dblk*16 + r] = O[dblk][r];
    const float lc = l + __shfl_xor(l, 32);
    if (lane < 32) lB[wl][lane] = lc;
  }
  __syncthreads();
  if (g){
    const float* src = cb + (size_t)(wl*64 + lane) * 33;
    const float lc = l + __shfl_xor(l, 32) + lB[wl][q31];
    if (lane < 32) Ls[w][lane] = 1.0f / lc;
    asm volatile("s_waitcnt lgkmcnt(0)" ::: "memory");
    #pragma unroll
    for (int r = 0; r < 16; ++r){
      const int qloc = (r&3) + 8*(r>>2) + 4*hi;
      const float inv = Ls[w][qloc];
      const size_t row = rowB + tB*128 + 32*wl + qloc;
      #pragma unroll
      for (int dblk = 0; dblk < 2; ++dblk)
        y[row * CEMB + h*64 + dblk*32 + q31] = f2bf((O[dblk][r] + src[dblk*16 + r]) * inv);
    }
  }
}

extern "C" void kernel_launch(void* const* d_in, const int* in_sizes, int n_in,
                              void* d_out, int out_size, void* d_ws, size_t ws_size,
                              hipStream_t stream)
{
  const float* x     = (const float*)d_in[0];
  const float* w_qkv = (const float*)d_in[1];
  const float* b_qkv = (const float*)d_in[2];
  const float* w_out = (const float*)d_in[3];
  const float* b_out = (const float*)d_in[4];
  float* out = (float*)d_out;

  char* ws = (char*)d_ws;
  unsigned short* xb    = (unsigned short*)(ws);                 // 16 MiB; dead after gemm1
  unsigned short* vTb   = (unsigned short*)(ws);                 // 16 MiB (reuses xb)
  unsigned short* qkvb  = (unsigned short*)(ws + (16u<<20));     // 48 MiB [8192,3072]
  unsigned short* yb    = (unsigned short*)(ws + (64u<<20));     // 16 MiB [8192,1024]
  unsigned short* wqkvT = (unsigned short*)(ws + (80u<<20));     //  6 MiB [3072,1024]
  unsigned short* woutT = (unsigned short*)(ws + (86u<<20));     //  2 MiB [1024,1024]

  const int M = 4 * TSEQ; // 8192

  k_prep<<<12288, 256, 0, stream>>>(x, xb, w_qkv, wqkvT, w_out, woutT);

  // QKV: 256x192 tiles -> 512 blocks = 2 full CU rounds
  k_gemm256<true, 192><<<dim3((M/256) * (3072/192)), 512, 0, stream>>>(xb, wqkvT, b_qkv, qkvb, M, 3072, 1024);
  k_vT<<<dim3(64, TSEQ/64), 256, 0, stream>>>(qkvb, vTb);
  k_attn<<<dim3(4 * 16, 8), 512, 0, stream>>>(qkvb, vTb, yb);
  // out-proj: 256x128 tiles -> 256 blocks = 1 full CU round
  k_gemm256<false, 128><<<dim3((M/256) * (1024/128)), 512, 0, stream>>>(yb, woutT, b_out, out, M, 1024, 1024);
}

// Round 10
// 166.727 us; speedup vs baseline: 1.0456x; 1.0456x over previous
//
#include <hip/hip_runtime.h>
#include <hip/hip_bf16.h>

#define TSEQ 2048
#define CEMB 1024

typedef __attribute__((ext_vector_type(8))) short bf16x8;
typedef __attribute__((ext_vector_type(4))) float f32x4;
typedef __attribute__((ext_vector_type(16))) float f32x16;
typedef __attribute__((ext_vector_type(4))) int i32x4;

__device__ __forceinline__ unsigned short f2bf(float f){
  return __builtin_bit_cast(unsigned short, __float2bfloat16(f));
}

__device__ __forceinline__ f32x4 MFMA16(bf16x8 a, bf16x8 b, f32x4 c){
  return __builtin_amdgcn_mfma_f32_16x16x32_bf16(a, b, c, 0, 0, 0);
}

#define GLDS(src, dst) __builtin_amdgcn_global_load_lds( \
      (const __attribute__((address_space(1))) void*)(src), \
      (__attribute__((address_space(3))) void*)(dst), 16, 0, 0)

template<int N> __device__ __forceinline__ void vmwait(){
  if constexpr (N == 0) asm volatile("s_waitcnt vmcnt(0)" ::: "memory");
  else if constexpr (N == 6) asm volatile("s_waitcnt vmcnt(6)" ::: "memory");
  else if constexpr (N == 7) asm volatile("s_waitcnt vmcnt(7)" ::: "memory");
  else asm volatile("s_waitcnt vmcnt(8)" ::: "memory");
}

// ---------- fused prep: x->bf16 cast + both weight transposes ----------
__global__ __launch_bounds__(256) void k_prep(
    const float* __restrict__ x, unsigned short* __restrict__ xb,
    const float* __restrict__ w_qkv, unsigned short* __restrict__ wqkvT,
    const float* __restrict__ w_out, unsigned short* __restrict__ woutT)
{
  __shared__ unsigned short tile[32][33];
  const int bid = blockIdx.x, tid = threadIdx.x;
  if (bid < 8192){
    const int i = bid * 256 + tid;
    const float4 v = reinterpret_cast<const float4*>(x)[i];
    ushort4 o;
    o.x = f2bf(v.x); o.y = f2bf(v.y); o.z = f2bf(v.z); o.w = f2bf(v.w);
    reinterpret_cast<ushort4*>(xb)[i] = o;
    return;
  }
  const float* w; unsigned short* wT; int N, n0, k0;
  if (bid < 11264){
    const int b2 = bid - 8192;           // 3072 blocks, N=3072
    w = w_qkv; wT = wqkvT; N = 3072;
    n0 = (b2 % 96) * 32; k0 = (b2 / 96) * 32;
  } else {
    const int b3 = bid - 11264;          // 1024 blocks, N=1024
    w = w_out; wT = woutT; N = 1024;
    n0 = (b3 & 31) * 32; k0 = (b3 >> 5) * 32;
  }
  const int tx = tid & 31, ty = tid >> 5;
  #pragma unroll
  for (int r = 0; r < 4; ++r){
    int k = ty * 4 + r;
    tile[k][tx] = f2bf(w[(size_t)(k0 + k) * N + n0 + tx]);
  }
  __syncthreads();
  #pragma unroll
  for (int r = 0; r < 4; ++r){
    int n = ty * 4 + r;
    wT[(size_t)(n0 + n) * 1024 + k0 + tx] = tile[tx][n];
  }
}

// ---------- V head-transpose: qkv[t][2048+h*64+d] -> vT[(bh*64+d)][t] ----------
__global__ __launch_bounds__(256) void k_vT(const unsigned short* __restrict__ qkv,
                                            unsigned short* __restrict__ vT){
  __shared__ __align__(16) unsigned short tile[64*64];
  const int tid = threadIdx.x;
  const int bh = blockIdx.x;          // b*16+h
  const int t0 = blockIdx.y * 64;
  const int b = bh >> 4, h = bh & 15;
  const int lt = tid >> 3, seg = tid & 7;
  #pragma unroll
  for (int r = 0; r < 2; ++r){
    const int t = lt + 32*r;
    const i32x4 v = *(const i32x4*)&qkv[((size_t)(b*TSEQ + t0 + t))*3072 + 2048 + h*64 + seg*8];
    const int slot = seg ^ (t & 7) ^ (t >> 3);
    *(i32x4*)((char*)tile + t*128 + slot*16) = v;
  }
  __syncthreads();
  const int w = tid >> 6, lane = tid & 63;
  const int tseg = lane & 7;
  #pragma unroll
  for (int r = 0; r < 2; ++r){
    const int d = w*8 + (lane>>3) + 32*r;
    unsigned int wd[4];
    #pragma unroll
    for (int jp = 0; jp < 4; ++jp){
      unsigned int lo, hi;
      #pragma unroll
      for (int e = 0; e < 2; ++e){
        const int j = jp*2 + e;
        const int t = tseg*8 + j;
        const int byteoff = t*128 + ((2*d) ^ (((j ^ tseg) & 7) << 4));
        const unsigned int val = *(const unsigned short*)((const char*)tile + byteoff);
        if (e == 0) lo = val; else hi = val;
      }
      wd[jp] = lo | (hi << 16);
    }
    i32x4 o4; o4[0]=wd[0]; o4[1]=wd[1]; o4[2]=wd[2]; o4[3]=wd[3];
    *(i32x4*)&vT[((size_t)bh*64 + d)*2048 + t0 + tseg*8] = o4;
  }
}

// ---------- GEMM 256xBN deep-pipelined (T1+T2+T3+T4+T5) — unchanged ----------
template<bool OUT_BF16, int BN>
__global__ __launch_bounds__(512, 2) void k_gemm256(
    const unsigned short* __restrict__ A,
    const unsigned short* __restrict__ Bt,
    const float* __restrict__ bias,
    void* __restrict__ Cout, int M, int N, int K)
{
  constexpr int NW  = BN / 64;
  constexpr int NH0 = (NW + 1) / 2;
  constexpr int NL  = 4 + NW;
  constexpr int BNB = BN * 128;
  __shared__ __align__(16) char smem[65536 + 2 * BNB];

  const int tid = threadIdx.x;
  const int lane = tid & 63, w = tid >> 6;
  const int wm = w >> 2, wn = w & 3;
  const int l15 = lane & 15, l4 = lane >> 4;
  const int x7 = l15 & 7;

  unsigned lin = blockIdx.x;
  {
    const unsigned nwg = gridDim.x;
    const unsigned qq = nwg >> 3, rr = nwg & 7;
    const unsigned xcd = lin & 7, loc = lin >> 3;
    lin = (xcd < rr ? xcd * (qq + 1) : rr * (qq + 1) + (xcd - rr) * qq) + loc;
  }
  const unsigned ntn = (unsigned)N / BN;
  const int m0 = (int)(lin / ntn) << 8;
  const int n0 = (int)(lin % ntn) * BN;

  const int srow = lane >> 3;
  const int scx  = (lane & 7) ^ srow;
  const unsigned short* Ag = A  + (size_t)(m0 + w*8 + srow) * K + scx * 8;
  const unsigned short* Bg = Bt + (size_t)(n0 + w*8 + srow) * K + scx * 8;

  auto stageA = [&](int buf, int kt){
    const unsigned short* s = Ag + kt*64;
    char* d = smem + buf*32768 + (w << 10);
    #pragma unroll
    for (int i = 0; i < 4; ++i) GLDS(s + (size_t)(i*64)*K, d + i*8192);
  };
  auto stageB = [&](int buf, int kt){
    const unsigned short* s = Bg + kt*64;
    char* d = smem + 65536 + buf*BNB + (w << 10);
    #pragma unroll
    for (int i = 0; i < NW; ++i) GLDS(s + (size_t)(i*64)*K, d + i*8192);
  };

  const int arow = wm*128 + l15;
  const int brow = wn*(BN/4) + l15;
  auto rdA = [&](int buf, int m, int ks)->bf16x8 {
    return *(const bf16x8*)(smem + buf*32768 + (arow + m*16)*128 + (((ks*4 + l4) ^ x7) << 4));
  };
  auto rdB = [&](int buf, int n, int ks)->bf16x8 {
    return *(const bf16x8*)(smem + 65536 + buf*BNB + (brow + n*16)*128 + (((ks*4 + l4) ^ x7) << 4));
  };

  f32x4 acc[8][NW] = {};
  const int NIT = K >> 7;

  stageA(0, 0); stageB(0, 0);
  stageA(1, 1); stageB(1, 1);
  vmwait<NL>();
  __builtin_amdgcn_s_barrier();
  asm volatile("" ::: "memory");

  for (int it = 0; it < NIT; ++it){
    const bool more = (it + 1 < NIT);
    #pragma unroll
    for (int half = 0; half < 2; ++half){
      const int buf = half;
      bf16x8 bfr[NW][2], af1[4][2], af2[4][2];
      #pragma unroll
      for (int n = 0; n < NW; ++n){ bfr[n][0] = rdB(buf, n, 0); bfr[n][1] = rdB(buf, n, 1); }
      #pragma unroll
      for (int m = 0; m < 4; ++m){ af1[m][0] = rdA(buf, m, 0); af1[m][1] = rdA(buf, m, 1); }
      __builtin_amdgcn_s_setprio(1);
      #pragma unroll
      for (int m = 0; m < 4; ++m)
        #pragma unroll
        for (int n = 0; n < NH0; ++n)
          #pragma unroll
          for (int ks = 0; ks < 2; ++ks)
            acc[m][n] = MFMA16(af1[m][ks], bfr[n][ks], acc[m][n]);
      __builtin_amdgcn_s_setprio(0);
      #pragma unroll
      for (int m = 0; m < 4; ++m){ af2[m][0] = rdA(buf, m+4, 0); af2[m][1] = rdA(buf, m+4, 1); }
      __builtin_amdgcn_s_setprio(1);
      #pragma unroll
      for (int m = 0; m < 4; ++m)
        #pragma unroll
        for (int n = NH0; n < NW; ++n)
          #pragma unroll
          for (int ks = 0; ks < 2; ++ks)
            acc[m][n] = MFMA16(af1[m][ks], bfr[n][ks], acc[m][n]);
      __builtin_amdgcn_s_setprio(0);
      __builtin_amdgcn_s_setprio(1);
      #pragma unroll
      for (int m = 0; m < 4; ++m)
        #pragma unroll
        for (int n = NH0; n < NW; ++n)
          #pragma unroll
          for (int ks = 0; ks < 2; ++ks)
            acc[m+4][n] = MFMA16(af2[m][ks], bfr[n][ks], acc[m+4][n]);
      __builtin_amdgcn_s_setprio(0);
      asm volatile("s_waitcnt lgkmcnt(0)" ::: "memory");
      __builtin_amdgcn_s_barrier();
      asm volatile("" ::: "memory");
      if (more){ stageA(buf, 2*it + half + 2); stageB(buf, 2*it + half + 2); }
      __builtin_amdgcn_s_setprio(1);
      #pragma unroll
      for (int m = 0; m < 4; ++m)
        #pragma unroll
        for (int n = 0; n < NH0; ++n)
          #pragma unroll
          for (int ks = 0; ks < 2; ++ks)
            acc[m+4][n] = MFMA16(af2[m][ks], bfr[n][ks], acc[m+4][n]);
      __builtin_amdgcn_s_setprio(0);
      if (more) vmwait<NL>();
      else      vmwait<0>();
      __builtin_amdgcn_s_barrier();
      asm volatile("" ::: "memory");
    }
  }

  float bv[NW];
  #pragma unroll
  for (int n = 0; n < NW; ++n) bv[n] = bias[n0 + wn*(BN/4) + n*16 + l15];

  #pragma unroll
  for (int m = 0; m < 8; ++m){
    const int row = m0 + wm*128 + m*16 + l4*4;
    #pragma unroll
    for (int n = 0; n < NW; ++n){
      const int col = n0 + wn*(BN/4) + n*16 + l15;
      #pragma unroll
      for (int r = 0; r < 4; ++r){
        float v = acc[m][n][r] + bv[n];
        if (OUT_BF16)
          ((unsigned short*)Cout)[(size_t)(row + r) * N + col] = f2bf(v);
        else
          ((float*)Cout)[(size_t)(row + r) * N + col] = v;
      }
    }
  }
}

// ---------- causal flash attention v7.1: balanced 17/17 split ----------
// IDENTICAL structure to v7; ONLY change: __launch_bounds__(512, 2).
// v7's (512,4) capped VGPR at 64 -> ~54 MB scratch spill per dispatch
// (WRITE_SIZE 70.6 MB vs 16.4 MB output). Grid is 512 blocks = 2/CU max
// anyway, so (512,2) costs nothing and restores a 128-VGPR budget.
__global__ __launch_bounds__(512, 2) void k_attn(
    const unsigned short* __restrict__ qkv,
    const unsigned short* __restrict__ vT,
    unsigned short* __restrict__ y)
{
  __shared__ __align__(16) char smem[65536];  // [group][buf][K|V] = 2*2*16KB
  __shared__ float Ls[8][32];
  __shared__ float lB[4][32];

  const int tid = threadIdx.x, lane = tid & 63, w = tid >> 6;  // w 0..7
  const int q31 = lane & 31, hi = lane >> 5;
  const int bh = blockIdx.x, p = blockIdx.y;    // p in [0,8)
  const int g = w >> 2, wl = w & 3;
  const int tA = p, tB = 15 - p;
  const int b = bh >> 4, h = bh & 15;
  const size_t rowB = (size_t)b * TSEQ;
  const int nktA = 2*p + 2;

  const float sc = 0.18033688011112042f;   // (1/sqrt(64)) * log2(e)

  // current-tile state (group A switches tiles mid-loop)
  int wq0 = (g ? tB : tA) * 128 + 32 * wl;

  bf16x8 qf[4];
  auto loadQ = [&](int qgx){
    const unsigned short* qp = qkv + (rowB + qgx) * 3072 + h * 64;
    #pragma unroll
    for (int c4 = 0; c4 < 4; ++c4){
      bf16x8 v = *(const bf16x8*)(qp + c4*16 + hi*8);
      #pragma unroll
      for (int j = 0; j < 8; ++j){
        const unsigned int bits = ((unsigned int)(unsigned short)v[j]) << 16;
        v[j] = (short)f2bf(__builtin_bit_cast(float, bits) * sc);
      }
      qf[c4] = v;
    }
  };
  loadQ(wq0 + q31);

  // group-local staging: 4 waves cover 64 rows x 8 chunks via 2 insts/matrix
  const int kr = lane >> 3, cx = (lane & 7) ^ kr;
  const unsigned short* kgbase = qkv + (rowB + wl*8 + kr) * 3072 + 1024 + h*64 + cx*8;
  const unsigned short* vgbase = vT + ((size_t)bh*64 + wl*8 + kr) * 2048 + cx*8;
  char* const gKV = smem + g*32768;

  auto stage = [&](int kv, int buf){
    char* kb = gKV + buf*16384;
    #pragma unroll
    for (int j = 0; j < 2; ++j){
      GLDS(kgbase + (size_t)kv*64*3072 + (size_t)j*32*3072, kb + j*4096 + wl*1024);
      GLDS(vgbase + (size_t)kv*64      + (size_t)j*32*2048, kb + 8192 + j*4096 + wl*1024);
    }
  };
  // work queue: group A: i<nktA ? i : i-nktA ; group B: i + 15-2p
  auto kv_of = [&](int i)->int {
    return g ? (i + 15 - 2*p) : (i < nktA ? i : i - nktA);
  };

  f32x16 O[2] = {};
  float l = 0.f;

  // wave-private finalize of current (O,l) -> y rows [wq0s, wq0s+32)
  auto storeY = [&](int wq0s){
    const float lc = l + __shfl_xor(l, 32);
    if (lane < 32) Ls[w][lane] = 1.0f / lc;
    asm volatile("s_waitcnt lgkmcnt(0)" ::: "memory");
    #pragma unroll
    for (int r = 0; r < 16; ++r){
      const int qloc = (r&3) + 8*(r>>2) + 4*hi;
      const float inv = Ls[w][qloc];
      const size_t row = rowB + wq0s + qloc;
      #pragma unroll
      for (int dblk = 0; dblk < 2; ++dblk)
        y[row * CEMB + h*64 + dblk*32 + q31] = f2bf(O[dblk][r] * inv);
    }
  };

  stage(kv_of(0), 0);
  __syncthreads();

  int cbuf = 0;
  for (int i = 0; i < 17; ++i){
    if (i + 1 < 17) stage(kv_of(i + 1), cbuf ^ 1);

    // group A: tile switch at i == nktA (finalize A, start B partials)
    if (!g && i == nktA){
      storeY(tA*128 + 32*wl);
      #pragma unroll
      for (int dblk = 0; dblk < 2; ++dblk) O[dblk] = (f32x16){};
      l = 0.f;
      wq0 = tB*128 + 32*wl;
      loadQ(wq0 + q31);
    }

    const int kv = kv_of(i);
    const int qg = wq0 + q31;
    const char* kb = gKV + cbuf*16384;
    const char* vb = kb + 8192;
    const bool domask = (kv*64 + 63 > wq0);
    #pragma unroll
    for (int sub = 0; sub < 2; ++sub){
      f32x16 S = {};
      __builtin_amdgcn_s_setprio(1);
      #pragma unroll
      for (int c4 = 0; c4 < 4; ++c4){
        const bf16x8 kf = *(const bf16x8*)(kb + (sub*32 + q31)*128
                              + ((((c4<<1)|hi) ^ (q31 & 7)) << 4));
        S = __builtin_amdgcn_mfma_f32_32x32x16_bf16(kf, qf[c4], S, 0, 0, 0);
      }
      __builtin_amdgcn_s_setprio(0);
      if (domask){
        #pragma unroll
        for (int r = 0; r < 16; ++r){
          const int kg = kv*64 + sub*32 + (r&3) + 8*(r>>2) + 4*hi;
          if (kg > qg) S[r] = -1e30f;
        }
      }
      float ps = 0.f;
      #pragma unroll
      for (int r = 0; r < 16; ++r){
        S[r] = __builtin_amdgcn_exp2f(S[r]);
        ps += S[r];
      }
      l += ps;
      bf16x8 paf[2];
      #pragma unroll
      for (int kc = 0; kc < 2; ++kc){
        const int e = kc * 8;
        unsigned int a, bb, cc, dd;
        asm("v_cvt_pk_bf16_f32 %0, %1, %2" : "=v"(a)  : "v"(S[e+0]), "v"(S[e+1]));
        asm("v_cvt_pk_bf16_f32 %0, %1, %2" : "=v"(bb) : "v"(S[e+4]), "v"(S[e+5]));
        asm("v_cvt_pk_bf16_f32 %0, %1, %2" : "=v"(cc) : "v"(S[e+2]), "v"(S[e+3]));
        asm("v_cvt_pk_bf16_f32 %0, %1, %2" : "=v"(dd) : "v"(S[e+6]), "v"(S[e+7]));
        asm volatile("v_permlane32_swap_b32 %0, %1" : "+v"(a),  "+v"(bb));
        asm volatile("v_permlane32_swap_b32 %0, %1" : "+v"(cc), "+v"(dd));
        i32x4 pwv; pwv[0] = (int)a; pwv[1] = (int)cc; pwv[2] = (int)bb; pwv[3] = (int)dd;
        paf[kc] = __builtin_bit_cast(bf16x8, pwv);
      }
      __builtin_amdgcn_s_setprio(1);
      #pragma unroll
      for (int kc = 0; kc < 2; ++kc){
        #pragma unroll
        for (int dblk = 0; dblk < 2; ++dblk){
          const int dr = dblk*32 + q31;
          const bf16x8 vf = *(const bf16x8*)(vb + dr*128
                                + ((((sub<<2)|(kc<<1)|hi) ^ (dr & 7)) << 4));
          O[dblk] = __builtin_amdgcn_mfma_f32_32x32x16_bf16(paf[kc], vf, O[dblk], 0, 0, 0);
        }
      }
      __builtin_amdgcn_s_setprio(0);
    }

    __syncthreads();   // drains gload_lds; publishes next buffer (both groups)
    cbuf ^= 1;
  }

  // ---- combine tile-B partials: group A -> LDS, group B adds & stores ----
  float* cb = (float*)smem;                       // staging done; reuse
  if (!g){
    float* dst = cb + (size_t)(wl*64 + lane) * 33;
    #pragma unroll
    for (int dblk = 0; dblk < 2; ++dblk)
      #pragma unroll
      for (int r = 0; r < 16; ++r) dst[dblk*16 + r] = O[dblk][r];
    const float lc = l + __shfl_xor(l, 32);
    if (lane < 32) lB[wl][lane] = lc;
  }
  __syncthreads();
  if (g){
    const float* src = cb + (size_t)(wl*64 + lane) * 33;
    const float lc = l + __shfl_xor(l, 32) + lB[wl][q31];
    if (lane < 32) Ls[w][lane] = 1.0f / lc;
    asm volatile("s_waitcnt lgkmcnt(0)" ::: "memory");
    #pragma unroll
    for (int r = 0; r < 16; ++r){
      const int qloc = (r&3) + 8*(r>>2) + 4*hi;
      const float inv = Ls[w][qloc];
      const size_t row = rowB + tB*128 + 32*wl + qloc;
      #pragma unroll
      for (int dblk = 0; dblk < 2; ++dblk)
        y[row * CEMB + h*64 + dblk*32 + q31] = f2bf((O[dblk][r] + src[dblk*16 + r]) * inv);
    }
  }
}

extern "C" void kernel_launch(void* const* d_in, const int* in_sizes, int n_in,
                              void* d_out, int out_size, void* d_ws, size_t ws_size,
                              hipStream_t stream)
{
  const float* x     = (const float*)d_in[0];
  const float* w_qkv = (const float*)d_in[1];
  const float* b_qkv = (const float*)d_in[2];
  const float* w_out = (const float*)d_in[3];
  const float* b_out = (const float*)d_in[4];
  float* out = (float*)d_out;

  char* ws = (char*)d_ws;
  unsigned short* xb    = (unsigned short*)(ws);                 // 16 MiB; dead after gemm1
  unsigned short* vTb   = (unsigned short*)(ws);                 // 16 MiB (reuses xb)
  unsigned short* qkvb  = (unsigned short*)(ws + (16u<<20));     // 48 MiB [8192,3072]
  unsigned short* yb    = (unsigned short*)(ws + (64u<<20));     // 16 MiB [8192,1024]
  unsigned short* wqkvT = (unsigned short*)(ws + (80u<<20));     //  6 MiB [3072,1024]
  unsigned short* woutT = (unsigned short*)(ws + (86u<<20));     //  2 MiB [1024,1024]

  const int M = 4 * TSEQ; // 8192

  k_prep<<<12288, 256, 0, stream>>>(x, xb, w_qkv, wqkvT, w_out, woutT);

  // QKV: 256x192 tiles -> 512 blocks = 2 full CU rounds
  k_gemm256<true, 192><<<dim3((M/256) * (3072/192)), 512, 0, stream>>>(xb, wqkvT, b_qkv, qkvb, M, 3072, 1024);
  k_vT<<<dim3(64, TSEQ/64), 256, 0, stream>>>(qkvb, vTb);
  k_attn<<<dim3(4 * 16, 8), 512, 0, stream>>>(qkvb, vTb, yb);
  // out-proj: 256x128 tiles -> 256 blocks = 1 full CU round
  k_gemm256<false, 128><<<dim3((M/256) * (1024/128)), 512, 0, stream>>>(yb, woutT, b_out, out, M, 1024, 1024);
}

// Round 11
// 161.552 us; speedup vs baseline: 1.0791x; 1.0320x over previous
//
#include <hip/hip_runtime.h>
#include <hip/hip_bf16.h>

#define TSEQ 2048
#define CEMB 1024

typedef __attribute__((ext_vector_type(8))) short bf16x8;
typedef __attribute__((ext_vector_type(4))) float f32x4;
typedef __attribute__((ext_vector_type(16))) float f32x16;
typedef __attribute__((ext_vector_type(4))) int i32x4;

__device__ __forceinline__ unsigned short f2bf(float f){
  return __builtin_bit_cast(unsigned short, __float2bfloat16(f));
}

__device__ __forceinline__ f32x4 MFMA16(bf16x8 a, bf16x8 b, f32x4 c){
  return __builtin_amdgcn_mfma_f32_16x16x32_bf16(a, b, c, 0, 0, 0);
}

#define GLDS(src, dst) __builtin_amdgcn_global_load_lds( \
      (const __attribute__((address_space(1))) void*)(src), \
      (__attribute__((address_space(3))) void*)(dst), 16, 0, 0)

template<int N> __device__ __forceinline__ void vmwait(){
  if constexpr (N == 0) asm volatile("s_waitcnt vmcnt(0)" ::: "memory");
  else if constexpr (N == 6) asm volatile("s_waitcnt vmcnt(6)" ::: "memory");
  else if constexpr (N == 7) asm volatile("s_waitcnt vmcnt(7)" ::: "memory");
  else asm volatile("s_waitcnt vmcnt(8)" ::: "memory");
}

// ---------- fused prep: x->bf16 cast + both weight transposes ----------
__global__ __launch_bounds__(256) void k_prep(
    const float* __restrict__ x, unsigned short* __restrict__ xb,
    const float* __restrict__ w_qkv, unsigned short* __restrict__ wqkvT,
    const float* __restrict__ w_out, unsigned short* __restrict__ woutT)
{
  __shared__ unsigned short tile[32][33];
  const int bid = blockIdx.x, tid = threadIdx.x;
  if (bid < 8192){
    const int i = bid * 256 + tid;
    const float4 v = reinterpret_cast<const float4*>(x)[i];
    ushort4 o;
    o.x = f2bf(v.x); o.y = f2bf(v.y); o.z = f2bf(v.z); o.w = f2bf(v.w);
    reinterpret_cast<ushort4*>(xb)[i] = o;
    return;
  }
  const float* w; unsigned short* wT; int N, n0, k0;
  if (bid < 11264){
    const int b2 = bid - 8192;           // 3072 blocks, N=3072
    w = w_qkv; wT = wqkvT; N = 3072;
    n0 = (b2 % 96) * 32; k0 = (b2 / 96) * 32;
  } else {
    const int b3 = bid - 11264;          // 1024 blocks, N=1024
    w = w_out; wT = woutT; N = 1024;
    n0 = (b3 & 31) * 32; k0 = (b3 >> 5) * 32;
  }
  const int tx = tid & 31, ty = tid >> 5;
  #pragma unroll
  for (int r = 0; r < 4; ++r){
    int k = ty * 4 + r;
    tile[k][tx] = f2bf(w[(size_t)(k0 + k) * N + n0 + tx]);
  }
  __syncthreads();
  #pragma unroll
  for (int r = 0; r < 4; ++r){
    int n = ty * 4 + r;
    wT[(size_t)(n0 + n) * 1024 + k0 + tx] = tile[tx][n];
  }
}

// ---------- V head-transpose: qkv[t][2048+h*64+d] -> vT[(bh*64+d)][t] ----------
__global__ __launch_bounds__(256) void k_vT(const unsigned short* __restrict__ qkv,
                                            unsigned short* __restrict__ vT){
  __shared__ __align__(16) unsigned short tile[64*64];
  const int tid = threadIdx.x;
  const int bh = blockIdx.x;          // b*16+h
  const int t0 = blockIdx.y * 64;
  const int b = bh >> 4, h = bh & 15;
  const int lt = tid >> 3, seg = tid & 7;
  #pragma unroll
  for (int r = 0; r < 2; ++r){
    const int t = lt + 32*r;
    const i32x4 v = *(const i32x4*)&qkv[((size_t)(b*TSEQ + t0 + t))*3072 + 2048 + h*64 + seg*8];
    const int slot = seg ^ (t & 7) ^ (t >> 3);
    *(i32x4*)((char*)tile + t*128 + slot*16) = v;
  }
  __syncthreads();
  const int w = tid >> 6, lane = tid & 63;
  const int tseg = lane & 7;
  #pragma unroll
  for (int r = 0; r < 2; ++r){
    const int d = w*8 + (lane>>3) + 32*r;
    unsigned int wd[4];
    #pragma unroll
    for (int jp = 0; jp < 4; ++jp){
      unsigned int lo, hi;
      #pragma unroll
      for (int e = 0; e < 2; ++e){
        const int j = jp*2 + e;
        const int t = tseg*8 + j;
        const int byteoff = t*128 + ((2*d) ^ (((j ^ tseg) & 7) << 4));
        const unsigned int val = *(const unsigned short*)((const char*)tile + byteoff);
        if (e == 0) lo = val; else hi = val;
      }
      wd[jp] = lo | (hi << 16);
    }
    i32x4 o4; o4[0]=wd[0]; o4[1]=wd[1]; o4[2]=wd[2]; o4[3]=wd[3];
    *(i32x4*)&vT[((size_t)bh*64 + d)*2048 + t0 + tseg*8] = o4;
  }
}

// ---------- GEMM 256xBN deep-pipelined (T1+T2+T3+T4+T5) — unchanged ----------
template<bool OUT_BF16, int BN>
__global__ __launch_bounds__(512, 2) void k_gemm256(
    const unsigned short* __restrict__ A,
    const unsigned short* __restrict__ Bt,
    const float* __restrict__ bias,
    void* __restrict__ Cout, int M, int N, int K)
{
  constexpr int NW  = BN / 64;
  constexpr int NH0 = (NW + 1) / 2;
  constexpr int NL  = 4 + NW;
  constexpr int BNB = BN * 128;
  __shared__ __align__(16) char smem[65536 + 2 * BNB];

  const int tid = threadIdx.x;
  const int lane = tid & 63, w = tid >> 6;
  const int wm = w >> 2, wn = w & 3;
  const int l15 = lane & 15, l4 = lane >> 4;
  const int x7 = l15 & 7;

  unsigned lin = blockIdx.x;
  {
    const unsigned nwg = gridDim.x;
    const unsigned qq = nwg >> 3, rr = nwg & 7;
    const unsigned xcd = lin & 7, loc = lin >> 3;
    lin = (xcd < rr ? xcd * (qq + 1) : rr * (qq + 1) + (xcd - rr) * qq) + loc;
  }
  const unsigned ntn = (unsigned)N / BN;
  const int m0 = (int)(lin / ntn) << 8;
  const int n0 = (int)(lin % ntn) * BN;

  const int srow = lane >> 3;
  const int scx  = (lane & 7) ^ srow;
  const unsigned short* Ag = A  + (size_t)(m0 + w*8 + srow) * K + scx * 8;
  const unsigned short* Bg = Bt + (size_t)(n0 + w*8 + srow) * K + scx * 8;

  auto stageA = [&](int buf, int kt){
    const unsigned short* s = Ag + kt*64;
    char* d = smem + buf*32768 + (w << 10);
    #pragma unroll
    for (int i = 0; i < 4; ++i) GLDS(s + (size_t)(i*64)*K, d + i*8192);
  };
  auto stageB = [&](int buf, int kt){
    const unsigned short* s = Bg + kt*64;
    char* d = smem + 65536 + buf*BNB + (w << 10);
    #pragma unroll
    for (int i = 0; i < NW; ++i) GLDS(s + (size_t)(i*64)*K, d + i*8192);
  };

  const int arow = wm*128 + l15;
  const int brow = wn*(BN/4) + l15;
  auto rdA = [&](int buf, int m, int ks)->bf16x8 {
    return *(const bf16x8*)(smem + buf*32768 + (arow + m*16)*128 + (((ks*4 + l4) ^ x7) << 4));
  };
  auto rdB = [&](int buf, int n, int ks)->bf16x8 {
    return *(const bf16x8*)(smem + 65536 + buf*BNB + (brow + n*16)*128 + (((ks*4 + l4) ^ x7) << 4));
  };

  f32x4 acc[8][NW] = {};
  const int NIT = K >> 7;

  stageA(0, 0); stageB(0, 0);
  stageA(1, 1); stageB(1, 1);
  vmwait<NL>();
  __builtin_amdgcn_s_barrier();
  asm volatile("" ::: "memory");

  for (int it = 0; it < NIT; ++it){
    const bool more = (it + 1 < NIT);
    #pragma unroll
    for (int half = 0; half < 2; ++half){
      const int buf = half;
      bf16x8 bfr[NW][2], af1[4][2], af2[4][2];
      #pragma unroll
      for (int n = 0; n < NW; ++n){ bfr[n][0] = rdB(buf, n, 0); bfr[n][1] = rdB(buf, n, 1); }
      #pragma unroll
      for (int m = 0; m < 4; ++m){ af1[m][0] = rdA(buf, m, 0); af1[m][1] = rdA(buf, m, 1); }
      __builtin_amdgcn_s_setprio(1);
      #pragma unroll
      for (int m = 0; m < 4; ++m)
        #pragma unroll
        for (int n = 0; n < NH0; ++n)
          #pragma unroll
          for (int ks = 0; ks < 2; ++ks)
            acc[m][n] = MFMA16(af1[m][ks], bfr[n][ks], acc[m][n]);
      __builtin_amdgcn_s_setprio(0);
      #pragma unroll
      for (int m = 0; m < 4; ++m){ af2[m][0] = rdA(buf, m+4, 0); af2[m][1] = rdA(buf, m+4, 1); }
      __builtin_amdgcn_s_setprio(1);
      #pragma unroll
      for (int m = 0; m < 4; ++m)
        #pragma unroll
        for (int n = NH0; n < NW; ++n)
          #pragma unroll
          for (int ks = 0; ks < 2; ++ks)
            acc[m][n] = MFMA16(af1[m][ks], bfr[n][ks], acc[m][n]);
      __builtin_amdgcn_s_setprio(0);
      __builtin_amdgcn_s_setprio(1);
      #pragma unroll
      for (int m = 0; m < 4; ++m)
        #pragma unroll
        for (int n = NH0; n < NW; ++n)
          #pragma unroll
          for (int ks = 0; ks < 2; ++ks)
            acc[m+4][n] = MFMA16(af2[m][ks], bfr[n][ks], acc[m+4][n]);
      __builtin_amdgcn_s_setprio(0);
      asm volatile("s_waitcnt lgkmcnt(0)" ::: "memory");
      __builtin_amdgcn_s_barrier();
      asm volatile("" ::: "memory");
      if (more){ stageA(buf, 2*it + half + 2); stageB(buf, 2*it + half + 2); }
      __builtin_amdgcn_s_setprio(1);
      #pragma unroll
      for (int m = 0; m < 4; ++m)
        #pragma unroll
        for (int n = 0; n < NH0; ++n)
          #pragma unroll
          for (int ks = 0; ks < 2; ++ks)
            acc[m+4][n] = MFMA16(af2[m][ks], bfr[n][ks], acc[m+4][n]);
      __builtin_amdgcn_s_setprio(0);
      if (more) vmwait<NL>();
      else      vmwait<0>();
      __builtin_amdgcn_s_barrier();
      asm volatile("" ::: "memory");
    }
  }

  float bv[NW];
  #pragma unroll
  for (int n = 0; n < NW; ++n) bv[n] = bias[n0 + wn*(BN/4) + n*16 + l15];

  #pragma unroll
  for (int m = 0; m < 8; ++m){
    const int row = m0 + wm*128 + m*16 + l4*4;
    #pragma unroll
    for (int n = 0; n < NW; ++n){
      const int col = n0 + wn*(BN/4) + n*16 + l15;
      #pragma unroll
      for (int r = 0; r < 4; ++r){
        float v = acc[m][n][r] + bv[n];
        if (OUT_BF16)
          ((unsigned short*)Cout)[(size_t)(row + r) * N + col] = f2bf(v);
        else
          ((float*)Cout)[(size_t)(row + r) * N + col] = v;
      }
    }
  }
}

// ---------- causal flash attention v8 = v6 structure, fixed launch params ----
// Folded-diagonal pairing, 8 waves/block: wavegroup 0 owns q-tile p, group 1
// owns 15-p; K/V staging SHARED (2 GLDS/thread/iter), 33 KB LDS.
// Changes vs v6: __launch_bounds__(512,3) (v6's (512,4) forced a 64-VGPR cap
// -> silent spill; 85 VGPR fits the ~75-reg live set, 3 blocks/CU = 24
// waves/CU), and grid (p fastest) so each CU's resident blocks mix heavy and
// light pairs (CU-level balance instead of v7's costly intra-block split).
__global__ __launch_bounds__(512, 3) void k_attn(
    const unsigned short* __restrict__ qkv,
    const unsigned short* __restrict__ vT,
    unsigned short* __restrict__ y)
{
  __shared__ __align__(16) char Ksm[2][8192];   // [key 64][128B], slot^=(key&7)
  __shared__ __align__(16) char Vsm[2][8192];   // [d 64][128B],  slot^=(d&7)
  __shared__ float Ls[8][32];

  const int tid = threadIdx.x, lane = tid & 63, w = tid >> 6;  // w 0..7
  const int q31 = lane & 31, hi = lane >> 5;
  const int p = blockIdx.x, bh = blockIdx.y;    // p in [0,8), bh in [0,64)
  const int g = w >> 2, wl = w & 3;
  const int myt = g ? (15 - p) : p;             // this wavegroup's q-tile
  const int b = bh >> 4, h = bh & 15;
  const size_t rowB = (size_t)b * TSEQ;

  const int wq0 = myt*128 + 32*wl, qg = wq0 + q31;
  const int nkt_my = 2*myt + 2;
  const int nktB  = 2*(15 - p) + 2;             // loop bound (heavy tile)

  const float sc = 0.18033688011112042f;   // (1/sqrt(64)) * log2(e)

  bf16x8 qf[4];
  {
    const unsigned short* qp = qkv + (rowB + qg) * 3072 + h * 64;
    #pragma unroll
    for (int c4 = 0; c4 < 4; ++c4){
      bf16x8 v = *(const bf16x8*)(qp + c4*16 + hi*8);
      #pragma unroll
      for (int j = 0; j < 8; ++j){
        const unsigned int bits = ((unsigned int)(unsigned short)v[j]) << 16;
        v[j] = (short)f2bf(__builtin_bit_cast(float, bits) * sc);
      }
      qf[c4] = v;
    }
  }

  // shared staging: 512 thr cover 64 rows x 8 chunks of K and V exactly once
  const int kr = lane >> 3, cx = (lane & 7) ^ kr;
  const unsigned short* kgbase = qkv + (rowB + w*8 + kr) * 3072 + 1024 + h*64 + cx*8;
  const unsigned short* vgbase = vT + ((size_t)bh*64 + w*8 + kr) * 2048 + cx*8;

  #define STAGE(ktile, buf)                                                          \
    do {                                                                             \
      GLDS(kgbase + (size_t)(ktile)*64*3072, &Ksm[buf][0] + w*1024);                 \
      GLDS(vgbase + (ktile)*64,              &Vsm[buf][0] + w*1024);                 \
    } while (0)

  f32x16 O[2] = {};
  float l = 0.f;

  STAGE(0, 0);
  __syncthreads();

  int cbuf = 0;
  for (int kt = 0; kt < nktB; ++kt){
    if (kt + 1 < nktB) STAGE(kt + 1, cbuf ^ 1);

    if (kt < nkt_my){
      const char* kb = Ksm[cbuf];
      const char* vb = Vsm[cbuf];
      const bool domask = (kt*64 + 63 > wq0);
      #pragma unroll
      for (int sub = 0; sub < 2; ++sub){
        f32x16 S = {};
        __builtin_amdgcn_s_setprio(1);
        #pragma unroll
        for (int c4 = 0; c4 < 4; ++c4){
          const bf16x8 kf = *(const bf16x8*)(kb + (sub*32 + q31)*128
                                + ((((c4<<1)|hi) ^ (q31 & 7)) << 4));
          S = __builtin_amdgcn_mfma_f32_32x32x16_bf16(kf, qf[c4], S, 0, 0, 0);
        }
        __builtin_amdgcn_s_setprio(0);
        if (domask){
          #pragma unroll
          for (int r = 0; r < 16; ++r){
            const int kg = kt*64 + sub*32 + (r&3) + 8*(r>>2) + 4*hi;
            if (kg > qg) S[r] = -1e30f;
          }
        }
        float ps = 0.f;
        #pragma unroll
        for (int r = 0; r < 16; ++r){
          S[r] = __builtin_amdgcn_exp2f(S[r]);   // shift-free; cancels in 1/l
          ps += S[r];
        }
        l += ps;
        bf16x8 paf[2];
        #pragma unroll
        for (int kc = 0; kc < 2; ++kc){
          const int e = kc * 8;
          unsigned int a, bb, cc, dd;
          asm("v_cvt_pk_bf16_f32 %0, %1, %2" : "=v"(a)  : "v"(S[e+0]), "v"(S[e+1]));
          asm("v_cvt_pk_bf16_f32 %0, %1, %2" : "=v"(bb) : "v"(S[e+4]), "v"(S[e+5]));
          asm("v_cvt_pk_bf16_f32 %0, %1, %2" : "=v"(cc) : "v"(S[e+2]), "v"(S[e+3]));
          asm("v_cvt_pk_bf16_f32 %0, %1, %2" : "=v"(dd) : "v"(S[e+6]), "v"(S[e+7]));
          asm volatile("v_permlane32_swap_b32 %0, %1" : "+v"(a),  "+v"(bb));
          asm volatile("v_permlane32_swap_b32 %0, %1" : "+v"(cc), "+v"(dd));
          i32x4 pwv; pwv[0] = (int)a; pwv[1] = (int)cc; pwv[2] = (int)bb; pwv[3] = (int)dd;
          paf[kc] = __builtin_bit_cast(bf16x8, pwv);
        }
        __builtin_amdgcn_s_setprio(1);
        #pragma unroll
        for (int kc = 0; kc < 2; ++kc){
          #pragma unroll
          for (int dblk = 0; dblk < 2; ++dblk){
            const int dr = dblk*32 + q31;
            const bf16x8 vf = *(const bf16x8*)(vb + dr*128
                                  + ((((sub<<2)|(kc<<1)|hi) ^ (dr & 7)) << 4));
            O[dblk] = __builtin_amdgcn_mfma_f32_32x32x16_bf16(paf[kc], vf, O[dblk], 0, 0, 0);
          }
        }
        __builtin_amdgcn_s_setprio(0);
      }
    }

    __syncthreads();   // drains global_load_lds + publishes next buffer
    cbuf ^= 1;
  }

  {
    const float lc = l + __shfl_xor(l, 32);
    if (lane < 32) Ls[w][lane] = 1.0f / lc;
  }
  __syncthreads();

  #pragma unroll
  for (int r = 0; r < 16; ++r){
    const int qloc = (r&3) + 8*(r>>2) + 4*hi;
    const float inv = Ls[w][qloc];
    const size_t row = rowB + wq0 + qloc;
    #pragma unroll
    for (int dblk = 0; dblk < 2; ++dblk)
      y[row * CEMB + h*64 + dblk*32 + q31] = f2bf(O[dblk][r] * inv);
  }
  #undef STAGE
}

extern "C" void kernel_launch(void* const* d_in, const int* in_sizes, int n_in,
                              void* d_out, int out_size, void* d_ws, size_t ws_size,
                              hipStream_t stream)
{
  const float* x     = (const float*)d_in[0];
  const float* w_qkv = (const float*)d_in[1];
  const float* b_qkv = (const float*)d_in[2];
  const float* w_out = (const float*)d_in[3];
  const float* b_out = (const float*)d_in[4];
  float* out = (float*)d_out;

  char* ws = (char*)d_ws;
  unsigned short* xb    = (unsigned short*)(ws);                 // 16 MiB; dead after gemm1
  unsigned short* vTb   = (unsigned short*)(ws);                 // 16 MiB (reuses xb)
  unsigned short* qkvb  = (unsigned short*)(ws + (16u<<20));     // 48 MiB [8192,3072]
  unsigned short* yb    = (unsigned short*)(ws + (64u<<20));     // 16 MiB [8192,1024]
  unsigned short* wqkvT = (unsigned short*)(ws + (80u<<20));     //  6 MiB [3072,1024]
  unsigned short* woutT = (unsigned short*)(ws + (86u<<20));     //  2 MiB [1024,1024]

  const int M = 4 * TSEQ; // 8192

  k_prep<<<12288, 256, 0, stream>>>(x, xb, w_qkv, wqkvT, w_out, woutT);

  // QKV: 256x192 tiles -> 512 blocks = 2 full CU rounds
  k_gemm256<true, 192><<<dim3((M/256) * (3072/192)), 512, 0, stream>>>(xb, wqkvT, b_qkv, qkvb, M, 3072, 1024);
  k_vT<<<dim3(64, TSEQ/64), 256, 0, stream>>>(qkvb, vTb);
  // attn: grid (p fastest) -> each CU's resident blocks mix heavy/light pairs
  k_attn<<<dim3(8, 4 * 16), 512, 0, stream>>>(qkvb, vTb, yb);
  // out-proj: 256x128 tiles -> 256 blocks = 1 full CU round
  k_gemm256<false, 128><<<dim3((M/256) * (1024/128)), 512, 0, stream>>>(yb, woutT, b_out, out, M, 1024, 1024);
}